// Round 10
// baseline (88.226 us; speedup 1.0000x reference)
//
#include <hip/hip_runtime.h>

typedef float f4 __attribute__((ext_vector_type(4)));
typedef float f2 __attribute__((ext_vector_type(2)));

#define PAD 68              // LDS row pitch (floats); 68%32=4 spreads banks
#define NPART 256           // gram blocks = partial count
#define PART_STRIDE 12288   // 3 * 64*64 floats per block partial

// ws layout (floats):
// [0, 3145728)      partials [256][3][4096]
// [3145728, +256)   bpart (K2)
// [3146240]         uint counter (K2 ticket; reset by K1 block 0)
// [3147776, +262144) diag sink (1 MB)

// ---------- DIAGNOSTIC: replicate K1's exact load pattern, 5 passes ----------
// Purpose: measure the achievable streaming rate of this grid shape. Sized
// (335 MB) to exceed the rocprof top-5 visibility threshold (~41 us) in all
// scenarios so its dispatch row (dur/FETCH/hbm_gbps) is readable next round.
__global__ __launch_bounds__(1024) void diag_kernel(
    const float* __restrict__ p1, const float* __restrict__ p2,
    float* __restrict__ sink)
{
    const int t = threadIdx.x;
    float acc = 0.f;
    for (int r = 0; r < 5; ++r) {
        const int eff = (blockIdx.x + r * 51) & 255;   // bijection per pass
        const int b   = eff >> 5;
        const int oi  = eff & 31;
        #pragma unroll
        for (int k = 0; k < 2; ++k) {
            const int idx = k * 1024 + t;
            const int c   = idx >> 5;
            const int oj  = idx & 31;
            const long off = (long)((b * 64 + c) * 128 + oi * 4) * 128 + oj * 4;
            const float* s1 = p1 + off;
            const float* s2 = p2 + off;
            f4 va = *(const f4*)(s1) + *(const f4*)(s1 + 128)
                  + *(const f4*)(s1 + 256) + *(const f4*)(s1 + 384);
            f4 vb = *(const f4*)(s2) + *(const f4*)(s2 + 128)
                  + *(const f4*)(s2 + 256) + *(const f4*)(s2 + 384);
            f4 s = va + vb;
            acc += (s[0] + s[1]) + (s[2] + s[3]);
        }
    }
    sink[blockIdx.x * 1024 + t] = acc;   // keep loads live; ws scratch only
}

// ---------- PRODUCTION: byte-identical to round 3 (35.2 us best) ----------
__global__ __launch_bounds__(1024) void fused_gram_kernel(
    const float* __restrict__ p1, const float* __restrict__ p2,
    float* __restrict__ partials, unsigned* __restrict__ cnt)
{
    __shared__ float la[32 * PAD];
    __shared__ float lb[32 * PAD];
    __shared__ float nred[64][17];
    __shared__ float sa[32], sb[32];
    const int t  = threadIdx.x;
    const int b  = blockIdx.x >> 5;   // batch 0..7
    const int oi = blockIdx.x & 31;   // pooled row strip 0..31

    if (blockIdx.x == 0 && t == 0) *cnt = 0u;   // reset K2's ticket each call

    #pragma unroll
    for (int k = 0; k < 2; ++k) {
        const int idx = k * 1024 + t;     // 0..2047
        const int c   = idx >> 5;
        const int oj  = idx & 31;
        const long off = (long)((b * 64 + c) * 128 + oi * 4) * 128 + oj * 4;
        const float* s1 = p1 + off;
        const float* s2 = p2 + off;
        f4 va = *(const f4*)(s1) + *(const f4*)(s1 + 128)
              + *(const f4*)(s1 + 256) + *(const f4*)(s1 + 384);
        f4 vb = *(const f4*)(s2) + *(const f4*)(s2 + 128)
              + *(const f4*)(s2 + 256) + *(const f4*)(s2 + 384);
        la[oj * PAD + c] = ((va[0] + va[1]) + (va[2] + va[3])) * 0.0625f;
        lb[oj * PAD + c] = ((vb[0] + vb[1]) + (vb[2] + vb[3])) * 0.0625f;
    }
    __syncthreads();

    {
        const int r = t & 31, g = t >> 5;
        const int m = g >> 4, q = g & 15;
        const float* src = m ? lb : la;
        float ss = 0.f;
        #pragma unroll
        for (int j = 0; j < 4; ++j) {
            const float v = src[r * PAD + q * 4 + j];
            ss = fmaf(v, v, ss);
        }
        nred[m * 32 + r][q] = ss;
    }
    __syncthreads();
    if (t < 64) {
        const int m = t >> 5, r = t & 31;
        float ss = 0.f;
        #pragma unroll
        for (int q = 0; q < 16; ++q) ss += nred[m * 32 + r][q];
        const float rs = 1.0f / fmaxf(sqrtf(ss), 1e-8f);
        if (m) sb[r] = rs; else sa[r] = rs;
    }
    __syncthreads();

    #pragma unroll
    for (int k = 0; k < 2; ++k) {
        const int idx = k * 1024 + t;
        const int c = idx >> 5, oj = idx & 31;
        la[oj * PAD + c] *= sa[oj];
        lb[oj * PAD + c] *= sb[oj];
    }
    __syncthreads();

    const int c1 = (t >> 5) * 2;
    const int c2 = (t & 31) * 2;
    f2 aa0 = {}, aa1 = {}, ab0 = {}, ab1 = {}, bb0 = {}, bb1 = {};

    #pragma unroll 8
    for (int r = 0; r < 32; ++r) {
        const f2 a1 = *(const f2*)&la[r * PAD + c1];
        const f2 a2 = *(const f2*)&la[r * PAD + c2];
        const f2 b1 = *(const f2*)&lb[r * PAD + c1];
        const f2 b2 = *(const f2*)&lb[r * PAD + c2];
        aa0 += a2 * a1[0];  aa1 += a2 * a1[1];
        ab0 += b2 * a1[0];  ab1 += b2 * a1[1];
        bb0 += b2 * b1[0];  bb1 += b2 * b1[1];
    }

    float* P = partials + (long)blockIdx.x * PART_STRIDE;
    *(f2*)&P[0 * 4096 + (c1    ) * 64 + c2] = aa0;
    *(f2*)&P[0 * 4096 + (c1 + 1) * 64 + c2] = aa1;
    *(f2*)&P[1 * 4096 + (c1    ) * 64 + c2] = ab0;
    *(f2*)&P[1 * 4096 + (c1 + 1) * 64 + c2] = ab1;
    *(f2*)&P[2 * 4096 + (c1    ) * 64 + c2] = bb0;
    *(f2*)&P[2 * 4096 + (c1 + 1) * 64 + c2] = bb1;
}

__global__ __launch_bounds__(256) void reduce_kernel(
    const float* __restrict__ partials, float* __restrict__ bpart,
    unsigned* __restrict__ cnt, float* __restrict__ out)
{
    __shared__ float red[3][16][17];
    __shared__ float vred[16];
    __shared__ float fr[256];
    __shared__ unsigned last_flag;
    const int t  = threadIdx.x;
    const int el = t & 15;
    const int pc = t >> 4;
    const int e  = blockIdx.x * 16 + el;

    float saa = 0.f, sab = 0.f, sbb = 0.f;
    #pragma unroll 4
    for (int i = 0; i < 16; ++i) {
        const float* P = partials + (long)(pc * 16 + i) * PART_STRIDE;
        saa += P[e];
        sab += P[4096 + e];
        sbb += P[8192 + e];
    }
    red[0][el][pc] = saa; red[1][el][pc] = sab; red[2][el][pc] = sbb;
    __syncthreads();

    if (t < 16) {
        float a = 0.f, m = 0.f, bv = 0.f;
        #pragma unroll
        for (int p = 0; p < 16; ++p) {
            a  += red[0][t][p];
            m  += red[1][t][p];
            bv += red[2][t][p];
        }
        vred[t] = fmaf(a, a, fmaf(bv, bv, -2.0f * (m * m)));
    }
    __syncthreads();

    if (t == 0) {
        float s = 0.f;
        #pragma unroll
        for (int i = 0; i < 16; ++i) s += vred[i];
        __hip_atomic_store(&bpart[blockIdx.x], s, __ATOMIC_RELEASE,
                           __HIP_MEMORY_SCOPE_AGENT);
        unsigned old = __hip_atomic_fetch_add(cnt, 1u, __ATOMIC_ACQ_REL,
                                              __HIP_MEMORY_SCOPE_AGENT);
        last_flag = (old == NPART - 1) ? 1u : 0u;
    }
    __syncthreads();

    if (last_flag) {
        fr[t] = __hip_atomic_load(&bpart[t], __ATOMIC_ACQUIRE,
                                  __HIP_MEMORY_SCOPE_AGENT);
        __syncthreads();
        for (int s2 = 128; s2 > 0; s2 >>= 1) {
            if (t < s2) fr[t] += fr[t + s2];
            __syncthreads();
        }
        if (t == 0) out[0] = fr[0] * (1.0f / 67108864.0f);  // / 8192^2
    }
}

extern "C" void kernel_launch(void* const* d_in, const int* in_sizes, int n_in,
                              void* d_out, int out_size, void* d_ws, size_t ws_size,
                              hipStream_t stream)
{
    const float* p1 = (const float*)d_in[0];
    const float* p2 = (const float*)d_in[1];
    float* ws       = (float*)d_ws;
    float* partials = ws;                                  // 256*12288
    float* bpart    = ws + (long)NPART * PART_STRIDE;      // 256
    unsigned* cnt   = (unsigned*)(ws + 3146240);           // 1
    float* sink     = ws + 3147776;                        // 1 MB diag scratch

    diag_kernel      <<<NPART, 1024, 0, stream>>>(p1, p2, sink);
    fused_gram_kernel<<<NPART, 1024, 0, stream>>>(p1, p2, partials, cnt);
    reduce_kernel    <<<NPART, 256, 0, stream>>>(partials, bpart, cnt, (float*)d_out);
}

// Round 11
// 33.671 us; speedup vs baseline: 2.6203x; 2.6203x over previous
//
#include <hip/hip_runtime.h>

typedef float f4 __attribute__((ext_vector_type(4)));
typedef float f2 __attribute__((ext_vector_type(2)));

#define PAD 68              // LDS row pitch (floats); 68%32=4 spreads banks
#define NPART 256           // gram blocks = partial count
#define PART_STRIDE 12288   // 3 * 64*64 floats per block partial

// ws layout (floats):
// [0, 3145728)      partials [256][3][4096]
// [3145728, +256)   bpart (K2)
// [3146240]         uint counter (K2 ticket; reset by K1 block 0)

// Barrier that does NOT drain outstanding global loads (prefetch survives):
// LDS ordering via lgkmcnt(0), then raw s_barrier; sched_barrier pins code
// motion so later ds ops can't hoist above the barrier.
__device__ __forceinline__ void lds_barrier() {
    asm volatile("s_waitcnt lgkmcnt(0)" ::: "memory");
    __builtin_amdgcn_s_barrier();
    __builtin_amdgcn_sched_barrier(0);
}

__global__ __launch_bounds__(1024) void fused_gram_kernel(
    const float* __restrict__ p1, const float* __restrict__ p2,
    float* __restrict__ partials, unsigned* __restrict__ cnt)
{
    __shared__ float la[2][8 * PAD];   // double-buffered 8-row tiles, input A
    __shared__ float lb[2][8 * PAD];   // and input B
    const int t  = threadIdx.x;
    const int b  = blockIdx.x >> 5;    // batch 0..7
    const int oi = blockIdx.x & 31;    // pooled row strip 0..31

    if (blockIdx.x == 0 && t == 0) *cnt = 0u;   // reset K2 ticket each call

    // --- per-thread pool slot: one pooled value per sub-strip ---
    const int m   = t >> 9;            // input select 0/1
    const int c   = (t >> 3) & 63;     // channel
    const int oj8 = t & 7;             // row within sub (8 lanes = 128B seg)
    const float* src = m ? p2 : p1;
    const long base = (long)((b * 64 + c) * 128 + oi * 4) * 128 + oj8 * 4;
    float* dst0 = m ? lb[0] : la[0];
    float* dst1 = m ? lb[1] : la[1];

    // --- norm-wave assignment: wave w owns row (nm, nr), lane = channel ---
    const int l  = t & 63;
    const int w  = t >> 6;
    const int nm = w >> 3, nr = w & 7;

    // --- gram 2x2 tile (r3-identical) ---
    const int c1 = (t >> 5) * 2;
    const int c2 = (t & 31) * 2;
    f2 aa0 = {}, aa1 = {}, ab0 = {}, ab1 = {}, bb0 = {}, bb1 = {};

    auto issue = [&](int q, f4& R0, f4& R1, f4& R2, f4& R3) {
        const float* s = src + base + q * 32;   // sub q: oj = q*8 + oj8
        R0 = *(const f4*)(s);
        R1 = *(const f4*)(s + 128);
        R2 = *(const f4*)(s + 256);
        R3 = *(const f4*)(s + 384);
    };
    auto pool = [&](const f4& R0, const f4& R1, const f4& R2, const f4& R3,
                    float* dst) {
        const f4 v = (R0 + R1) + (R2 + R3);
        dst[oj8 * PAD + c] = ((v[0] + v[1]) + (v[2] + v[3])) * 0.0625f;
    };
    auto normphase = [&](int bi) {     // 16 waves: reduce + rescale in place
        float* rowp = (nm ? lb[bi] : la[bi]) + nr * PAD;
        const float v = rowp[l];
        float ss = v * v;
        ss += __shfl_xor(ss, 1);
        ss += __shfl_xor(ss, 2);
        ss += __shfl_xor(ss, 4);
        ss += __shfl_xor(ss, 8);
        ss += __shfl_xor(ss, 16);
        ss += __shfl_xor(ss, 32);
        rowp[l] = v * (1.0f / fmaxf(sqrtf(ss), 1e-8f));
    };
    auto gram = [&](int bi) {
        #pragma unroll
        for (int r = 0; r < 8; ++r) {
            const f2 a1 = *(const f2*)&la[bi][r * PAD + c1];
            const f2 a2 = *(const f2*)&la[bi][r * PAD + c2];
            const f2 b1 = *(const f2*)&lb[bi][r * PAD + c1];
            const f2 b2 = *(const f2*)&lb[bi][r * PAD + c2];
            aa0 += a2 * a1[0];  aa1 += a2 * a1[1];
            ab0 += b2 * a1[0];  ab1 += b2 * a1[1];
            bb0 += b2 * b1[0];  bb1 += b2 * b1[1];
        }
    };

    // ---- software pipeline, depth 2: loads for sub q+1/q+2 in flight
    // while sub q is pooled/normed/grammed. lds_barrier does NOT wait vmcnt.
    f4 A0, A1, A2, A3, B0, B1, B2, B3;
    issue(0, A0, A1, A2, A3);
    issue(1, B0, B1, B2, B3);

    pool(A0, A1, A2, A3, dst0);  lds_barrier();
    normphase(0);                lds_barrier();
    issue(2, A0, A1, A2, A3);    // A regs dead after pool; refill for sub 2
    gram(0);

    pool(B0, B1, B2, B3, dst1);  lds_barrier();
    normphase(1);                lds_barrier();
    issue(3, B0, B1, B2, B3);
    gram(1);

    pool(A0, A1, A2, A3, dst0);  lds_barrier();
    normphase(0);                lds_barrier();
    gram(0);

    pool(B0, B1, B2, B3, dst1);  lds_barrier();
    normphase(1);                lds_barrier();
    gram(1);

    // ---- partial store: byte-identical layout to round 3 ----
    float* P = partials + (long)blockIdx.x * PART_STRIDE;
    *(f2*)&P[0 * 4096 + (c1    ) * 64 + c2] = aa0;
    *(f2*)&P[0 * 4096 + (c1 + 1) * 64 + c2] = aa1;
    *(f2*)&P[1 * 4096 + (c1    ) * 64 + c2] = ab0;
    *(f2*)&P[1 * 4096 + (c1 + 1) * 64 + c2] = ab1;
    *(f2*)&P[2 * 4096 + (c1    ) * 64 + c2] = bb0;
    *(f2*)&P[2 * 4096 + (c1 + 1) * 64 + c2] = bb1;
}

// K2: byte-identical to round 3's (best measured): 256 blocks x 256 threads.
__global__ __launch_bounds__(256) void reduce_kernel(
    const float* __restrict__ partials, float* __restrict__ bpart,
    unsigned* __restrict__ cnt, float* __restrict__ out)
{
    __shared__ float red[3][16][17];
    __shared__ float vred[16];
    __shared__ float fr[256];
    __shared__ unsigned last_flag;
    const int t  = threadIdx.x;
    const int el = t & 15;
    const int pc = t >> 4;
    const int e  = blockIdx.x * 16 + el;

    float saa = 0.f, sab = 0.f, sbb = 0.f;
    #pragma unroll 4
    for (int i = 0; i < 16; ++i) {
        const float* P = partials + (long)(pc * 16 + i) * PART_STRIDE;
        saa += P[e];
        sab += P[4096 + e];
        sbb += P[8192 + e];
    }
    red[0][el][pc] = saa; red[1][el][pc] = sab; red[2][el][pc] = sbb;
    __syncthreads();

    if (t < 16) {
        float a = 0.f, mm = 0.f, bv = 0.f;
        #pragma unroll
        for (int p = 0; p < 16; ++p) {
            a  += red[0][t][p];
            mm += red[1][t][p];
            bv += red[2][t][p];
        }
        vred[t] = fmaf(a, a, fmaf(bv, bv, -2.0f * (mm * mm)));
    }
    __syncthreads();

    if (t == 0) {
        float s = 0.f;
        #pragma unroll
        for (int i = 0; i < 16; ++i) s += vred[i];
        __hip_atomic_store(&bpart[blockIdx.x], s, __ATOMIC_RELEASE,
                           __HIP_MEMORY_SCOPE_AGENT);
        unsigned old = __hip_atomic_fetch_add(cnt, 1u, __ATOMIC_ACQ_REL,
                                              __HIP_MEMORY_SCOPE_AGENT);
        last_flag = (old == NPART - 1) ? 1u : 0u;
    }
    __syncthreads();

    if (last_flag) {   // block-uniform
        fr[t] = __hip_atomic_load(&bpart[t], __ATOMIC_ACQUIRE,
                                  __HIP_MEMORY_SCOPE_AGENT);
        __syncthreads();
        for (int s2 = 128; s2 > 0; s2 >>= 1) {
            if (t < s2) fr[t] += fr[t + s2];
            __syncthreads();
        }
        if (t == 0) out[0] = fr[0] * (1.0f / 67108864.0f);  // / 8192^2
    }
}

extern "C" void kernel_launch(void* const* d_in, const int* in_sizes, int n_in,
                              void* d_out, int out_size, void* d_ws, size_t ws_size,
                              hipStream_t stream)
{
    const float* p1 = (const float*)d_in[0];
    const float* p2 = (const float*)d_in[1];
    float* ws       = (float*)d_ws;
    float* partials = ws;                                  // 256*12288
    float* bpart    = ws + (long)NPART * PART_STRIDE;      // 256
    unsigned* cnt   = (unsigned*)(ws + 3146240);           // 1

    fused_gram_kernel<<<NPART, 1024, 0, stream>>>(p1, p2, partials, cnt);
    reduce_kernel   <<<NPART, 256, 0, stream>>>(partials, bpart, cnt, (float*)d_out);
}